// Round 11
// baseline (257.137 us; speedup 1.0000x reference)
//
#include <hip/hip_runtime.h>
#include <hip/hip_bf16.h>

#define N_PTS 50000
#define NNB   32
#define KP    15
#define DIN   64
#define DOUT  1024
#define KDIM  (KP*DIN)    // 960
#define NB    16
#define SIGMA_INV (1.0f/0.3f)

#define BM 128
#define BN 32
#define BK 32
#define RB_FULL 392                 // worst-case row blocks (50176 rows)
#define NSEG 196                    // 256-point segments

typedef __attribute__((ext_vector_type(8))) short bf16x8;
typedef __attribute__((ext_vector_type(4))) float f32x4;

#define GLD16(gsrc, ldst) \
  __builtin_amdgcn_global_load_lds((const __attribute__((address_space(1))) char*)(gsrc), \
                                   (__attribute__((address_space(3))) char*)(ldst), 16, 0, 0)

// ---------------- Kernel 0: W transpose to bf16 [1024][960]; zeroes bcnt -----
__global__ __launch_bounds__(256) void wt_kernel(
    const float* __restrict__ W, __hip_bfloat16* __restrict__ Wt,
    int* __restrict__ bcnt) {
  if (blockIdx.x == 0 && blockIdx.y == 0 && threadIdx.x < 256)
    bcnt[threadIdx.x] = 0;                      // runs before kpconv (stream order)
  __shared__ float t[64][65];
  int k0 = blockIdx.x * 64;
  int o0 = blockIdx.y * 64;
  int tx = threadIdx.x & 63, ty = threadIdx.x >> 6;
  for (int r = ty; r < 64; r += 4) t[r][tx] = W[(size_t)(k0 + r)*DOUT + o0 + tx];
  __syncthreads();
  for (int r = ty; r < 64; r += 4)
    Wt[(size_t)(o0 + r)*KDIM + k0 + tx] = __float2bfloat16(t[tx][r]);
}

// ---------------- Kernel 1: KPConv full — flag + g row, one wave/point ------
// h_lds is k-major [16][33] (pad) -> per-lane stride-1 writes, conflict-free.
__global__ __launch_bounds__(256) void kpconv_full_kernel(
    const float* __restrict__ pos, const float* __restrict__ feats,
    const float* __restrict__ kpts, const int* __restrict__ nidx,
    __hip_bfloat16* __restrict__ g, int* __restrict__ flag,
    int* __restrict__ bcnt) {
  __shared__ float h_lds[4][16][33];
  __shared__ int cnts;
  int tid = threadIdx.x;
  int w = tid >> 6, lane = tid & 63;
  if (tid == 0) cnts = 0;
  __syncthreads();
  int n = blockIdx.x * 4 + w;
  if (n < N_PTS) {
    int myj = lane & 31;
    int khalf = lane >> 5;
    int id0 = nidx[n*NNB + myj];
    float px = pos[n*3+0], py = pos[n*3+1], pz = pos[n*3+2];
    float rx = pos[id0*3+0] - px;
    float ry = pos[id0*3+1] - py;
    float rz = pos[id0*3+2] - pz;
    bool anyact = false;
    float hreg[8];
    #pragma unroll
    for (int i = 0; i < 8; ++i) {
      int k = 2*i + khalf;
      float h = 0.0f;
      if (k < KP) {
        float dx = rx - kpts[k*3+0];
        float dy = ry - kpts[k*3+1];
        float dz = rz - kpts[k*3+2];
        float d = sqrtf(dx*dx + dy*dy + dz*dz);
        h = 1.0f - d * SIGMA_INV;
        h = h > 0.0f ? h : 0.0f;
        anyact |= (h > 0.0f);
      }
      hreg[i] = h;
    }
    unsigned long long bal = __ballot(anyact);
    if (bal) {                                  // wave-uniform
      unsigned int actj = (unsigned int)(bal | (bal >> 32));
      if ((actj >> myj) & 1) {                  // either half-lane active -> j read
        #pragma unroll
        for (int i = 0; i < 8; ++i) {
          int k = 2*i + khalf;
          if (k < KP) h_lds[w][k][myj] = hreg[i];
        }
      }
      float acc[KP];
      #pragma unroll
      for (int k = 0; k < KP; ++k) acc[k] = 0.0f;
      while (actj) {
        int j = __ffs(actj) - 1;
        actj &= actj - 1;
        int id = __shfl(id0, j);
        float f = feats[(size_t)id*DIN + lane];
        #pragma unroll
        for (int k = 0; k < KP; ++k) acc[k] += h_lds[w][k][j] * f;
      }
      size_t base = (size_t)n*KDIM;
      #pragma unroll
      for (int k = 0; k < KP; ++k)
        g[base + k*DIN + lane] = __float2bfloat16(acc[k]);
    }
    if (lane == 0) {
      int active = (bal != 0ull) ? 1 : 0;
      flag[n] = active;
      if (active) atomicAdd(&cnts, 1);
    }
  }
  __syncthreads();
  if (tid == 0 && cnts) atomicAdd(&bcnt[blockIdx.x >> 6], cnts);
}

// ---------------- Kernel S: scan 196 segment counts (1 block) ---------------
__global__ __launch_bounds__(256) void scan_kernel(
    const int* __restrict__ blockcnt, int* __restrict__ blockoff,
    int* __restrict__ mact) {
  __shared__ int s[256];
  int tid = threadIdx.x;
  int own = (tid < NSEG) ? blockcnt[tid] : 0;
  s[tid] = own;
  __syncthreads();
  for (int d = 1; d < 256; d <<= 1) {
    int v = (tid >= d) ? s[tid-d] : 0;
    __syncthreads();
    s[tid] += v;
    __syncthreads();
  }
  if (tid < NSEG) blockoff[tid] = s[tid] - own;   // exclusive
  if (tid == NSEG-1) *mact = s[tid];
}

// ---------------- Kernel C0: fill rowlist + compact batch ids ---------------
__global__ __launch_bounds__(256) void fill_kernel(
    const int* __restrict__ flag, const int* __restrict__ blockoff,
    const int* __restrict__ batch, int* __restrict__ rowlist,
    int* __restrict__ bidc) {
  __shared__ int s[256];
  int tid = threadIdx.x;
  int n = blockIdx.x*256 + tid;
  int f = (n < N_PTS) ? flag[n] : 0;
  s[tid] = f;
  __syncthreads();
  for (int d = 1; d < 256; d <<= 1) {
    int v = (tid >= d) ? s[tid-d] : 0;
    __syncthreads();
    s[tid] += v;
    __syncthreads();
  }
  if (f) {
    int sl = blockoff[blockIdx.x] + s[tid] - 1;
    rowlist[sl] = n;
    bidc[sl] = batch[n];
  }
}

// ---------------- Kernel 2: MFMA GEMM (gathered A rows) + fused pool --------
// 128x32 tile, BK=32, 4 waves 2x2 (each 64x16 out), 4 MFMA/iter/wave.
// Active blocks ~102rb x 32cb = 3264 -> ~12.75/CU (R2's proven TLP regime).
// Grid (392,32): linear id = rb + 392*cb, 392%8==0 -> all cb blocks of one
// A-panel on ONE XCD. Tail slots guarded by Ma (no memset needed).
__global__ __launch_bounds__(256) void gemm_mfma_pool(
    const __hip_bfloat16* __restrict__ g, const __hip_bfloat16* __restrict__ Wt,
    const int* __restrict__ rowlist, const int* __restrict__ bidc,
    const int* __restrict__ mact, float* __restrict__ partial) {
  __shared__ __align__(16) char lA[BM*64];   // 8KB
  __shared__ __align__(16) char lB[BN*64];   // 2KB
  __shared__ float psum[NB][BN];             // 2KB
  __shared__ int bid[BM];
  int rb = blockIdx.x, cb = blockIdx.y;
  int Ma = *mact;
  int r0 = rb*BM, c0 = cb*BN;
  int tid = threadIdx.x;
  if (r0 >= Ma) return;
  int lane = tid & 63, w = tid >> 6;
  int wr = w >> 1, wc = w & 1;

  // hoisted gather bases (per-lane global src is legal for global_load_lds)
  int ra = tid >> 2;
  int kg = (tid & 3) ^ ((ra >> 1) & 3);
  int row0 = (r0 + ra < Ma)      ? rowlist[r0 + ra]      : 0;
  int row1 = (r0 + 64 + ra < Ma) ? rowlist[r0 + 64 + ra] : 0;
  const char* pA0 = (const char*)(g + (size_t)row0*KDIM) + kg*16;
  const char* pA1 = (const char*)(g + (size_t)row1*KDIM) + kg*16;
  int rowB = (tid >> 2) & 31;
  int kgB = (tid & 3) ^ ((rowB >> 1) & 3);
  const char* pB = (const char*)(Wt + (size_t)(c0 + rowB)*KDIM) + kgB*16;

  if (tid < BM) bid[tid] = (r0 + tid < Ma) ? bidc[r0 + tid] : -1;
  for (int z = tid; z < NB*BN; z += 256) (&psum[0][0])[z] = 0.0f;

  f32x4 acc[4] = {};

  for (int k0 = 0; k0 < KDIM; k0 += BK) {
    GLD16(pA0 + k0*2, lA + tid*16);
    GLD16(pA1 + k0*2, lA + (256 + tid)*16);
    if (tid < 128) GLD16(pB + k0*2, lB + tid*16);   // waves 0,1 fully active
    __syncthreads();
    bf16x8 af[4], bfr;
    #pragma unroll
    for (int m = 0; m < 4; ++m) {
      int row = wr*64 + m*16 + (lane & 15);
      int slot = (lane >> 4) ^ ((row >> 1) & 3);
      af[m] = *(const bf16x8*)(lA + row*64 + slot*16);
    }
    {
      int row = wc*16 + (lane & 15);
      int slot = (lane >> 4) ^ ((row >> 1) & 3);
      bfr = *(const bf16x8*)(lB + row*64 + slot*16);
    }
    #pragma unroll
    for (int m = 0; m < 4; ++m)
      acc[m] = __builtin_amdgcn_mfma_f32_16x16x32_bf16(af[m], bfr, acc[m], 0, 0, 0);
    __syncthreads();
  }

  // ---- epilogue: leaky + deterministic per-batch column sums ----
  int q = lane >> 4;
  #pragma unroll 1
  for (int phase = 0; phase < 8; ++phase) {
    if (wr*4 + q == phase) {
      int c = wc*16 + (lane & 15);
      float run = 0.0f; int curb = -2;
      #pragma unroll
      for (int m = 0; m < 4; ++m) {
        #pragma unroll
        for (int j = 0; j < 4; ++j) {
          int r = wr*64 + m*16 + q*4 + j;
          int b = bid[r];
          float v = acc[m][j];
          v = v > 0.0f ? v : 0.1f*v;
          if (b != curb) { if (curb >= 0) psum[curb][c] += run; run = 0.0f; curb = b; }
          run += v;
        }
      }
      if (curb >= 0) psum[curb][c] += run;
    }
    __syncthreads();
  }
  for (int z = tid; z < NB*BN; z += 256) {
    int b = z >> 5, c = z & 31;
    partial[((size_t)rb*NB + b)*DOUT + c0 + c] = psum[b][c];
  }
}

// ---------------- Kernel 3: fused reduce+mean+MLP layer 1 (split-K) ---------
// Block (s,b): reduces its own 128 pooled cols over active rb, then 128-dot.
__global__ __launch_bounds__(512) void mlpA_kernel(
    const float* __restrict__ partial, const int* __restrict__ batch,
    const int* __restrict__ mact, const float* __restrict__ w1,
    float* __restrict__ part1) {
  __shared__ float pl[128];
  int s = blockIdx.x, b = blockIdx.y, t = threadIdx.x;
  int nact = (*mact + BM - 1) / BM;
  if (t < 128) {
    float v = 0.0f;
    for (int rb = 0; rb < nact; ++rb)
      v += partial[((size_t)rb*NB + b)*DOUT + s*128 + t];
    int lb, ub;
    { int l = 0, r = N_PTS; while (l < r) { int m = (l+r)>>1; if (batch[m] <  b) l = m+1; else r = m; } lb = l; }
    { int l = 0, r = N_PTS; while (l < r) { int m = (l+r)>>1; if (batch[m] <= b) l = m+1; else r = m; } ub = l; }
    pl[t] = v / fmaxf((float)(ub - lb), 1.0f);
  }
  __syncthreads();
  float acc = 0.0f;
  #pragma unroll 8
  for (int i = 0; i < 128; ++i) acc += pl[i] * w1[(size_t)(s*128 + i)*512 + t];
  part1[((size_t)b*8 + s)*512 + t] = acc;
}

// ---------------- Kernel 4: fused MLP layers 2+3 ----------------------------
__global__ __launch_bounds__(256) void mlpBC_kernel(
    const float* __restrict__ part1, const float* __restrict__ b1,
    const float* __restrict__ w2, const float* __restrict__ b2,
    const float* __restrict__ w3, const float* __restrict__ b3,
    float* __restrict__ out) {
  __shared__ float hs[512];
  __shared__ float h2l[256];
  int b = blockIdx.x, t = threadIdx.x;
  for (int u = t; u < 512; u += 256) {
    float v = b1[u];
    #pragma unroll
    for (int s = 0; s < 8; ++s) v += part1[((size_t)b*8 + s)*512 + u];
    hs[u] = fmaxf(v, 0.0f);
  }
  __syncthreads();
  float a2 = b2[t];
  #pragma unroll 8
  for (int j = 0; j < 512; ++j) a2 += hs[j] * w2[(size_t)j*256 + t];
  h2l[t] = fmaxf(a2, 0.0f);
  __syncthreads();
  if (t < 152) {
    float a3 = b3[t];
    #pragma unroll 8
    for (int i = 0; i < 256; ++i) a3 += h2l[i] * w3[i*152 + t];
    out[b*152 + t] = a3;
  }
}

// ---------------- launch -----------------------------------------------------
extern "C" void kernel_launch(void* const* d_in, const int* in_sizes, int n_in,
                              void* d_out, int out_size, void* d_ws, size_t ws_size,
                              hipStream_t stream) {
  (void)in_sizes; (void)n_in; (void)out_size; (void)ws_size;
  const float* pos   = (const float*)d_in[0];
  const float* feats = (const float*)d_in[1];
  const float* kpts  = (const float*)d_in[2];
  const float* kpw   = (const float*)d_in[3];
  const float* w1    = (const float*)d_in[4];
  const float* b1    = (const float*)d_in[5];
  const float* w2    = (const float*)d_in[6];
  const float* b2    = (const float*)d_in[7];
  const float* w3    = (const float*)d_in[8];
  const float* b3    = (const float*)d_in[9];
  const int* nidx    = (const int*)d_in[10];
  const int* batch   = (const int*)d_in[11];
  float* out = (float*)d_out;

  char* ws = (char*)d_ws;
  const size_t off_g        = 0;                         // 50000*960*2 = 96,000,000
  const size_t off_bidc     = 96000000;                  // 200,704
  const size_t off_rowlist  = off_bidc + 200704;
  const size_t off_flag     = off_rowlist + 200704;
  const size_t off_bcnt     = off_flag + 200704;         // 1024
  const size_t off_boff     = off_bcnt + 1024;           // 1024
  const size_t off_mact     = off_boff + 1024;           // 64
  const size_t off_wt       = off_mact + 64;             // 1,966,080
  const size_t off_partial  = off_wt + 1966080;          // 392*16*1024*4 = 25,690,112
  const size_t off_p1       = off_partial + 25690112;    // 262,144  (total ~124.5MB)
  __hip_bfloat16* g  = (__hip_bfloat16*)(ws + off_g);
  int* bidc    = (int*)(ws + off_bidc);
  int* rowlist = (int*)(ws + off_rowlist);
  int* flag    = (int*)(ws + off_flag);
  int* bcnt    = (int*)(ws + off_bcnt);
  int* boff    = (int*)(ws + off_boff);
  int* mact    = (int*)(ws + off_mact);
  __hip_bfloat16* wt = (__hip_bfloat16*)(ws + off_wt);
  float* partial = (float*)(ws + off_partial);
  float* part1   = (float*)(ws + off_p1);

  wt_kernel<<<dim3(KDIM/64, DOUT/64), 256, 0, stream>>>(kpw, wt, bcnt);
  kpconv_full_kernel<<<N_PTS/4, 256, 0, stream>>>(pos, feats, kpts, nidx, g, flag, bcnt);
  scan_kernel<<<1, 256, 0, stream>>>(bcnt, boff, mact);
  fill_kernel<<<NSEG, 256, 0, stream>>>(flag, boff, batch, rowlist, bidc);
  gemm_mfma_pool<<<dim3(RB_FULL, DOUT/BN), 256, 0, stream>>>(g, wt, rowlist, bidc, mact, partial);
  mlpA_kernel<<<dim3(8, NB), 512, 0, stream>>>(partial, batch, mact, w1, part1);
  mlpBC_kernel<<<NB, 256, 0, stream>>>(part1, b1, w2, b2, w3, b3, out);
}

// Round 12
// 226.010 us; speedup vs baseline: 1.1377x; 1.1377x over previous
//
#include <hip/hip_runtime.h>
#include <hip/hip_bf16.h>

#define N_PTS 50000
#define NNB   32
#define KP    15
#define DIN   64
#define DOUT  1024
#define KDIM  (KP*DIN)    // 960
#define NB    16
#define SIGMA_INV (1.0f/0.3f)

#define BM 128
#define BN 64
#define BK 64
#define NKT (KDIM/BK)               // 15
#define RB_FULL 392                 // worst-case row blocks (50176 rows)
#define NSEG 196                    // 256-point segments

typedef __attribute__((ext_vector_type(8))) short bf16x8;
typedef __attribute__((ext_vector_type(4))) float f32x4;

#define GLD16(gsrc, ldst) \
  __builtin_amdgcn_global_load_lds((const __attribute__((address_space(1))) char*)(gsrc), \
                                   (__attribute__((address_space(3))) char*)(ldst), 16, 0, 0)

// ---------------- Kernel 0: W transpose to bf16 [1024][960]; zeroes bcnt -----
__global__ __launch_bounds__(256) void wt_kernel(
    const float* __restrict__ W, __hip_bfloat16* __restrict__ Wt,
    int* __restrict__ bcnt) {
  if (blockIdx.x == 0 && blockIdx.y == 0 && threadIdx.x < 256)
    bcnt[threadIdx.x] = 0;                      // runs before kpconv (stream order)
  __shared__ float t[64][65];
  int k0 = blockIdx.x * 64;
  int o0 = blockIdx.y * 64;
  int tx = threadIdx.x & 63, ty = threadIdx.x >> 6;
  for (int r = ty; r < 64; r += 4) t[r][tx] = W[(size_t)(k0 + r)*DOUT + o0 + tx];
  __syncthreads();
  for (int r = ty; r < 64; r += 4)
    Wt[(size_t)(o0 + r)*KDIM + k0 + tx] = __float2bfloat16(t[tx][r]);
}

// ---------------- Kernel 1: KPConv full — flag + g row, one wave/point ------
// h_lds is k-major [16][33] (pad) -> conflict-free writes/broadcast reads.
__global__ __launch_bounds__(256) void kpconv_full_kernel(
    const float* __restrict__ pos, const float* __restrict__ feats,
    const float* __restrict__ kpts, const int* __restrict__ nidx,
    __hip_bfloat16* __restrict__ g, int* __restrict__ flag,
    int* __restrict__ bcnt) {
  __shared__ float h_lds[4][16][33];
  __shared__ int cnts;
  int tid = threadIdx.x;
  int w = tid >> 6, lane = tid & 63;
  if (tid == 0) cnts = 0;
  __syncthreads();
  int n = blockIdx.x * 4 + w;
  if (n < N_PTS) {
    int myj = lane & 31;
    int khalf = lane >> 5;
    int id0 = nidx[n*NNB + myj];
    float px = pos[n*3+0], py = pos[n*3+1], pz = pos[n*3+2];
    float rx = pos[id0*3+0] - px;
    float ry = pos[id0*3+1] - py;
    float rz = pos[id0*3+2] - pz;
    bool anyact = false;
    float hreg[8];
    #pragma unroll
    for (int i = 0; i < 8; ++i) {
      int k = 2*i + khalf;
      float h = 0.0f;
      if (k < KP) {
        float dx = rx - kpts[k*3+0];
        float dy = ry - kpts[k*3+1];
        float dz = rz - kpts[k*3+2];
        float d = sqrtf(dx*dx + dy*dy + dz*dz);
        h = 1.0f - d * SIGMA_INV;
        h = h > 0.0f ? h : 0.0f;
        anyact |= (h > 0.0f);
      }
      hreg[i] = h;
    }
    unsigned long long bal = __ballot(anyact);
    if (bal) {                                  // wave-uniform
      unsigned int actj = (unsigned int)(bal | (bal >> 32));
      if ((actj >> myj) & 1) {
        #pragma unroll
        for (int i = 0; i < 8; ++i) {
          int k = 2*i + khalf;
          if (k < KP) h_lds[w][k][myj] = hreg[i];
        }
      }
      float acc[KP];
      #pragma unroll
      for (int k = 0; k < KP; ++k) acc[k] = 0.0f;
      while (actj) {
        int j = __ffs(actj) - 1;
        actj &= actj - 1;
        int id = __shfl(id0, j);
        float f = feats[(size_t)id*DIN + lane];
        #pragma unroll
        for (int k = 0; k < KP; ++k) acc[k] += h_lds[w][k][j] * f;
      }
      size_t base = (size_t)n*KDIM;
      #pragma unroll
      for (int k = 0; k < KP; ++k)
        g[base + k*DIN + lane] = __float2bfloat16(acc[k]);
    }
    if (lane == 0) {
      int active = (bal != 0ull) ? 1 : 0;
      flag[n] = active;
      if (active) atomicAdd(&cnts, 1);
    }
  }
  __syncthreads();
  if (tid == 0 && cnts) atomicAdd(&bcnt[blockIdx.x >> 6], cnts);
}

// ---------------- Kernel S: scan 196 segment counts (1 block) ---------------
__global__ __launch_bounds__(256) void scan_kernel(
    const int* __restrict__ blockcnt, int* __restrict__ blockoff,
    int* __restrict__ mact) {
  __shared__ int s[256];
  int tid = threadIdx.x;
  int own = (tid < NSEG) ? blockcnt[tid] : 0;
  s[tid] = own;
  __syncthreads();
  for (int d = 1; d < 256; d <<= 1) {
    int v = (tid >= d) ? s[tid-d] : 0;
    __syncthreads();
    s[tid] += v;
    __syncthreads();
  }
  if (tid < NSEG) blockoff[tid] = s[tid] - own;   // exclusive
  if (tid == NSEG-1) *mact = s[tid];
}

// ---------------- Kernel C0: fill rowlist + compact batch ids ---------------
__global__ __launch_bounds__(256) void fill_kernel(
    const int* __restrict__ flag, const int* __restrict__ blockoff,
    const int* __restrict__ batch, int* __restrict__ rowlist,
    int* __restrict__ bidc) {
  __shared__ int s[256];
  int tid = threadIdx.x;
  int n = blockIdx.x*256 + tid;
  int f = (n < N_PTS) ? flag[n] : 0;
  s[tid] = f;
  __syncthreads();
  for (int d = 1; d < 256; d <<= 1) {
    int v = (tid >= d) ? s[tid-d] : 0;
    __syncthreads();
    s[tid] += v;
    __syncthreads();
  }
  if (f) {
    int sl = blockoff[blockIdx.x] + s[tid] - 1;
    rowlist[sl] = n;
    bidc[sl] = batch[n];
  }
}

// ---------------- Kernel 2: MFMA GEMM (gathered A rows) + fused pool --------
// 128x64 tile, BK=64 (15 iters, half the barrier drains of BK=32), 4 waves
// 2x2 (each 64x32 out, 16 MFMA/iter). 128B LDS rows, chunk-XOR swizzle
// (R5/R6/R7-verified 0-conflict): store global chunk c^(row&7) at slot c,
// read slot ch^(row&7). gc is uniform across a thread's 4 staged A-rows.
// Grid (392,16): linear id = rb + 392*cb, 392%8==0 -> all cb blocks of one
// A-panel on ONE XCD.
__global__ __launch_bounds__(256) void gemm_mfma_pool(
    const __hip_bfloat16* __restrict__ g, const __hip_bfloat16* __restrict__ Wt,
    const int* __restrict__ rowlist, const int* __restrict__ bidc,
    const int* __restrict__ mact, float* __restrict__ partial) {
  __shared__ __align__(16) char lA[BM*128];  // 16KB
  __shared__ __align__(16) char lB[BN*128];  // 8KB
  __shared__ float psum[NB][BN];             // 4KB
  __shared__ int bid[BM];
  int rb = blockIdx.x, cb = blockIdx.y;
  int Ma = *mact;
  int r0 = rb*BM, c0 = cb*BN;
  int tid = threadIdx.x;
  if (r0 >= Ma) return;
  int lane = tid & 63, w = tid >> 6;
  int wr = w >> 1, wc = w & 1;

  // hoisted gather bases; gc = (tid&7)^((tid>>3)&7) uniform over i (32%8==0)
  int gc = (tid & 7) ^ ((tid >> 3) & 7);
  const __hip_bfloat16* pA[4];
  #pragma unroll
  for (int i = 0; i < 4; ++i) {
    int slot = r0 + i*32 + (tid >> 3);
    int rl = (slot < Ma) ? rowlist[slot] : 0;
    pA[i] = g + (size_t)rl*KDIM + gc*8;
  }
  const __hip_bfloat16* pB[2];
  #pragma unroll
  for (int i = 0; i < 2; ++i)
    pB[i] = Wt + (size_t)(c0 + i*32 + (tid >> 3))*KDIM + gc*8;

  if (tid < BM) bid[tid] = (r0 + tid < Ma) ? bidc[r0 + tid] : -1;
  for (int z = tid; z < NB*BN; z += 256) (&psum[0][0])[z] = 0.0f;

  f32x4 acc[4][2] = {};

  for (int kt = 0; kt < NKT; ++kt) {
    int k0 = kt*BK;
    #pragma unroll
    for (int i = 0; i < 4; ++i) GLD16(pA[i] + k0, lA + (i*256 + tid)*16);
    #pragma unroll
    for (int i = 0; i < 2; ++i) GLD16(pB[i] + k0, lB + (i*256 + tid)*16);
    __syncthreads();
    #pragma unroll
    for (int ks = 0; ks < 2; ++ks) {
      bf16x8 af[4], bfr[2];
      #pragma unroll
      for (int m = 0; m < 4; ++m) {
        int row = wr*64 + m*16 + (lane & 15);
        int ch = (ks*4 + (lane >> 4)) ^ (row & 7);
        af[m] = *(const bf16x8*)(lA + row*128 + ch*16);
      }
      #pragma unroll
      for (int n = 0; n < 2; ++n) {
        int row = wc*32 + n*16 + (lane & 15);
        int ch = (ks*4 + (lane >> 4)) ^ (row & 7);
        bfr[n] = *(const bf16x8*)(lB + row*128 + ch*16);
      }
      #pragma unroll
      for (int m = 0; m < 4; ++m)
        #pragma unroll
        for (int n = 0; n < 2; ++n)
          acc[m][n] = __builtin_amdgcn_mfma_f32_16x16x32_bf16(af[m], bfr[n], acc[m][n], 0, 0, 0);
    }
    __syncthreads();
  }

  // ---- epilogue: leaky + deterministic per-batch column sums ----
  int q = lane >> 4;
  #pragma unroll 1
  for (int phase = 0; phase < 8; ++phase) {
    if (wr*4 + q == phase) {
      #pragma unroll
      for (int n = 0; n < 2; ++n) {
        int c = wc*32 + n*16 + (lane & 15);
        float run = 0.0f; int curb = -2;
        #pragma unroll
        for (int m = 0; m < 4; ++m) {
          #pragma unroll
          for (int j = 0; j < 4; ++j) {
            int r = wr*64 + m*16 + q*4 + j;
            int b = bid[r];
            float v = acc[m][n][j];
            v = v > 0.0f ? v : 0.1f*v;
            if (b != curb) { if (curb >= 0) psum[curb][c] += run; run = 0.0f; curb = b; }
            run += v;
          }
        }
        if (curb >= 0) psum[curb][c] += run;
      }
    }
    __syncthreads();
  }
  for (int z = tid; z < NB*BN; z += 256) {
    int b = z >> 6, c = z & 63;
    partial[((size_t)rb*NB + b)*DOUT + c0 + c] = psum[b][c];
  }
}

// ---------------- Kernel 3: fused reduce+mean+MLP layer 1 (split-K) ---------
__global__ __launch_bounds__(512) void mlpA_kernel(
    const float* __restrict__ partial, const int* __restrict__ batch,
    const int* __restrict__ mact, const float* __restrict__ w1,
    float* __restrict__ part1) {
  __shared__ float pl[128];
  int s = blockIdx.x, b = blockIdx.y, t = threadIdx.x;
  int nact = (*mact + BM - 1) / BM;
  if (t < 128) {
    float v = 0.0f;
    for (int rb = 0; rb < nact; ++rb)
      v += partial[((size_t)rb*NB + b)*DOUT + s*128 + t];
    int lb, ub;
    { int l = 0, r = N_PTS; while (l < r) { int m = (l+r)>>1; if (batch[m] <  b) l = m+1; else r = m; } lb = l; }
    { int l = 0, r = N_PTS; while (l < r) { int m = (l+r)>>1; if (batch[m] <= b) l = m+1; else r = m; } ub = l; }
    pl[t] = v / fmaxf((float)(ub - lb), 1.0f);
  }
  __syncthreads();
  float acc = 0.0f;
  #pragma unroll 8
  for (int i = 0; i < 128; ++i) acc += pl[i] * w1[(size_t)(s*128 + i)*512 + t];
  part1[((size_t)b*8 + s)*512 + t] = acc;
}

// ---------------- Kernel 4: fused MLP layers 2+3 ----------------------------
__global__ __launch_bounds__(256) void mlpBC_kernel(
    const float* __restrict__ part1, const float* __restrict__ b1,
    const float* __restrict__ w2, const float* __restrict__ b2,
    const float* __restrict__ w3, const float* __restrict__ b3,
    float* __restrict__ out) {
  __shared__ float hs[512];
  __shared__ float h2l[256];
  int b = blockIdx.x, t = threadIdx.x;
  for (int u = t; u < 512; u += 256) {
    float v = b1[u];
    #pragma unroll
    for (int s = 0; s < 8; ++s) v += part1[((size_t)b*8 + s)*512 + u];
    hs[u] = fmaxf(v, 0.0f);
  }
  __syncthreads();
  float a2 = b2[t];
  #pragma unroll 8
  for (int j = 0; j < 512; ++j) a2 += hs[j] * w2[(size_t)j*256 + t];
  h2l[t] = fmaxf(a2, 0.0f);
  __syncthreads();
  if (t < 152) {
    float a3 = b3[t];
    #pragma unroll 8
    for (int i = 0; i < 256; ++i) a3 += h2l[i] * w3[i*152 + t];
    out[b*152 + t] = a3;
  }
}

// ---------------- launch -----------------------------------------------------
extern "C" void kernel_launch(void* const* d_in, const int* in_sizes, int n_in,
                              void* d_out, int out_size, void* d_ws, size_t ws_size,
                              hipStream_t stream) {
  (void)in_sizes; (void)n_in; (void)out_size; (void)ws_size;
  const float* pos   = (const float*)d_in[0];
  const float* feats = (const float*)d_in[1];
  const float* kpts  = (const float*)d_in[2];
  const float* kpw   = (const float*)d_in[3];
  const float* w1    = (const float*)d_in[4];
  const float* b1    = (const float*)d_in[5];
  const float* w2    = (const float*)d_in[6];
  const float* b2    = (const float*)d_in[7];
  const float* w3    = (const float*)d_in[8];
  const float* b3    = (const float*)d_in[9];
  const int* nidx    = (const int*)d_in[10];
  const int* batch   = (const int*)d_in[11];
  float* out = (float*)d_out;

  char* ws = (char*)d_ws;
  const size_t off_g        = 0;                         // 50000*960*2 = 96,000,000
  const size_t off_bidc     = 96000000;                  // 200,704
  const size_t off_rowlist  = off_bidc + 200704;
  const size_t off_flag     = off_rowlist + 200704;
  const size_t off_bcnt     = off_flag + 200704;         // 1024
  const size_t off_boff     = off_bcnt + 1024;           // 1024
  const size_t off_mact     = off_boff + 1024;           // 64
  const size_t off_wt       = off_mact + 64;             // 1,966,080
  const size_t off_partial  = off_wt + 1966080;          // 392*16*1024*4 = 25,690,112
  const size_t off_p1       = off_partial + 25690112;    // 262,144
  __hip_bfloat16* g  = (__hip_bfloat16*)(ws + off_g);
  int* bidc    = (int*)(ws + off_bidc);
  int* rowlist = (int*)(ws + off_rowlist);
  int* flag    = (int*)(ws + off_flag);
  int* bcnt    = (int*)(ws + off_bcnt);
  int* boff    = (int*)(ws + off_boff);
  int* mact    = (int*)(ws + off_mact);
  __hip_bfloat16* wt = (__hip_bfloat16*)(ws + off_wt);
  float* partial = (float*)(ws + off_partial);
  float* part1   = (float*)(ws + off_p1);

  wt_kernel<<<dim3(KDIM/64, DOUT/64), 256, 0, stream>>>(kpw, wt, bcnt);
  kpconv_full_kernel<<<(N_PTS+3)/4, 256, 0, stream>>>(pos, feats, kpts, nidx, g, flag, bcnt);
  scan_kernel<<<1, 256, 0, stream>>>(bcnt, boff, mact);
  fill_kernel<<<NSEG, 256, 0, stream>>>(flag, boff, batch, rowlist, bidc);
  gemm_mfma_pool<<<dim3(RB_FULL, DOUT/BN), 256, 0, stream>>>(g, wt, rowlist, bidc, mact, partial);
  mlpA_kernel<<<dim3(8, NB), 512, 0, stream>>>(partial, batch, mact, w1, part1);
  mlpBC_kernel<<<NB, 256, 0, stream>>>(part1, b1, w2, b2, w3, b3, out);
}

// Round 13
// 206.541 us; speedup vs baseline: 1.2450x; 1.0943x over previous
//
#include <hip/hip_runtime.h>
#include <hip/hip_bf16.h>

#define N_PTS 50000
#define NNB   32
#define KP    15
#define DIN   64
#define DOUT  1024
#define KDIM  (KP*DIN)    // 960
#define NB    16
#define SIGMA_INV (1.0f/0.3f)

#define BM 64
#define BN 64
#define BK 64
#define NKT (KDIM/BK)               // 15
#define RB_FULL 784                 // worst-case row blocks (50176 rows), %8==0
#define NSEG 196                    // 256-point segments

typedef __attribute__((ext_vector_type(8))) short bf16x8;
typedef __attribute__((ext_vector_type(4))) float f32x4;

#define GLD16(gsrc, ldst) \
  __builtin_amdgcn_global_load_lds((const __attribute__((address_space(1))) char*)(gsrc), \
                                   (__attribute__((address_space(3))) char*)(ldst), 16, 0, 0)

// ---------------- Kernel 0: W transpose to bf16 [1024][960]; zeroes bcnt -----
__global__ __launch_bounds__(256) void wt_kernel(
    const float* __restrict__ W, __hip_bfloat16* __restrict__ Wt,
    int* __restrict__ bcnt) {
  if (blockIdx.x == 0 && blockIdx.y == 0 && threadIdx.x < 256)
    bcnt[threadIdx.x] = 0;                      // runs before kpconv (stream order)
  __shared__ float t[64][65];
  int k0 = blockIdx.x * 64;
  int o0 = blockIdx.y * 64;
  int tx = threadIdx.x & 63, ty = threadIdx.x >> 6;
  for (int r = ty; r < 64; r += 4) t[r][tx] = W[(size_t)(k0 + r)*DOUT + o0 + tx];
  __syncthreads();
  for (int r = ty; r < 64; r += 4)
    Wt[(size_t)(o0 + r)*KDIM + k0 + tx] = __float2bfloat16(t[tx][r]);
}

// ---------------- Kernel 1: KPConv full — flag + g row, one wave/point ------
__global__ __launch_bounds__(256) void kpconv_full_kernel(
    const float* __restrict__ pos, const float* __restrict__ feats,
    const float* __restrict__ kpts, const int* __restrict__ nidx,
    __hip_bfloat16* __restrict__ g, int* __restrict__ flag,
    int* __restrict__ bcnt) {
  __shared__ float h_lds[4][16][33];
  __shared__ int cnts;
  int tid = threadIdx.x;
  int w = tid >> 6, lane = tid & 63;
  if (tid == 0) cnts = 0;
  __syncthreads();
  int n = blockIdx.x * 4 + w;
  if (n < N_PTS) {
    int myj = lane & 31;
    int khalf = lane >> 5;
    int id0 = nidx[n*NNB + myj];
    float px = pos[n*3+0], py = pos[n*3+1], pz = pos[n*3+2];
    float rx = pos[id0*3+0] - px;
    float ry = pos[id0*3+1] - py;
    float rz = pos[id0*3+2] - pz;
    bool anyact = false;
    float hreg[8];
    #pragma unroll
    for (int i = 0; i < 8; ++i) {
      int k = 2*i + khalf;
      float h = 0.0f;
      if (k < KP) {
        float dx = rx - kpts[k*3+0];
        float dy = ry - kpts[k*3+1];
        float dz = rz - kpts[k*3+2];
        float d = sqrtf(dx*dx + dy*dy + dz*dz);
        h = 1.0f - d * SIGMA_INV;
        h = h > 0.0f ? h : 0.0f;
        anyact |= (h > 0.0f);
      }
      hreg[i] = h;
    }
    unsigned long long bal = __ballot(anyact);
    if (bal) {                                  // wave-uniform
      unsigned int actj = (unsigned int)(bal | (bal >> 32));
      if ((actj >> myj) & 1) {
        #pragma unroll
        for (int i = 0; i < 8; ++i) {
          int k = 2*i + khalf;
          if (k < KP) h_lds[w][k][myj] = hreg[i];
        }
      }
      float acc[KP];
      #pragma unroll
      for (int k = 0; k < KP; ++k) acc[k] = 0.0f;
      while (actj) {
        int j = __ffs(actj) - 1;
        actj &= actj - 1;
        int id = __shfl(id0, j);
        float f = feats[(size_t)id*DIN + lane];
        #pragma unroll
        for (int k = 0; k < KP; ++k) acc[k] += h_lds[w][k][j] * f;
      }
      size_t base = (size_t)n*KDIM;
      #pragma unroll
      for (int k = 0; k < KP; ++k)
        g[base + k*DIN + lane] = __float2bfloat16(acc[k]);
    }
    if (lane == 0) {
      int active = (bal != 0ull) ? 1 : 0;
      flag[n] = active;
      if (active) atomicAdd(&cnts, 1);
    }
  }
  __syncthreads();
  if (tid == 0 && cnts) atomicAdd(&bcnt[blockIdx.x >> 6], cnts);
}

// ---------------- Kernel S: scan 196 segment counts (1 block) ---------------
__global__ __launch_bounds__(256) void scan_kernel(
    const int* __restrict__ blockcnt, int* __restrict__ blockoff,
    int* __restrict__ mact) {
  __shared__ int s[256];
  int tid = threadIdx.x;
  int own = (tid < NSEG) ? blockcnt[tid] : 0;
  s[tid] = own;
  __syncthreads();
  for (int d = 1; d < 256; d <<= 1) {
    int v = (tid >= d) ? s[tid-d] : 0;
    __syncthreads();
    s[tid] += v;
    __syncthreads();
  }
  if (tid < NSEG) blockoff[tid] = s[tid] - own;   // exclusive
  if (tid == NSEG-1) *mact = s[tid];
}

// ---------------- Kernel C0: fill rowlist + compact batch ids ---------------
__global__ __launch_bounds__(256) void fill_kernel(
    const int* __restrict__ flag, const int* __restrict__ blockoff,
    const int* __restrict__ batch, int* __restrict__ rowlist,
    int* __restrict__ bidc) {
  __shared__ int s[256];
  int tid = threadIdx.x;
  int n = blockIdx.x*256 + tid;
  int f = (n < N_PTS) ? flag[n] : 0;
  s[tid] = f;
  __syncthreads();
  for (int d = 1; d < 256; d <<= 1) {
    int v = (tid >= d) ? s[tid-d] : 0;
    __syncthreads();
    s[tid] += v;
    __syncthreads();
  }
  if (f) {
    int sl = blockoff[blockIdx.x] + s[tid] - 1;
    rowlist[sl] = n;
    bidc[sl] = batch[n];
  }
}

// ---------------- Kernel 2: MFMA GEMM (gathered A rows) + fused pool --------
// 64x64 tile, BK=64, 4 waves 2x2 (each 32x32 out, 8 MFMA/iter). Active
// blocks ~204rb x 16cb = 3264 -> 12.75/CU (R2's proven TLP regime); LDS
// 20.3KB -> 7 resident/CU. 128B LDS rows, chunk-XOR swizzle (verified
// 0-conflict). Grid (784,16): linear id = rb + 784*cb, 784%8==0 -> all cb
// blocks sharing an A-panel land on ONE XCD.
__global__ __launch_bounds__(256) void gemm_mfma_pool(
    const __hip_bfloat16* __restrict__ g, const __hip_bfloat16* __restrict__ Wt,
    const int* __restrict__ rowlist, const int* __restrict__ bidc,
    const int* __restrict__ mact, float* __restrict__ partial) {
  __shared__ __align__(16) char lA[BM*128];  // 8KB
  __shared__ __align__(16) char lB[BN*128];  // 8KB
  __shared__ float psum[NB][BN];             // 4KB
  __shared__ int bid[BM];
  int rb = blockIdx.x, cb = blockIdx.y;
  int Ma = *mact;
  int r0 = rb*BM, c0 = cb*BN;
  int tid = threadIdx.x;
  if (r0 >= Ma) return;
  int lane = tid & 63, w = tid >> 6;
  int wr = w >> 1, wc = w & 1;

  // hoisted gather bases; gc uniform over i (rows i*32+(tid>>3), 32%8==0)
  int gc = (tid & 7) ^ ((tid >> 3) & 7);
  const __hip_bfloat16* pA[2];
  #pragma unroll
  for (int i = 0; i < 2; ++i) {
    int slot = r0 + i*32 + (tid >> 3);
    int rl = (slot < Ma) ? rowlist[slot] : 0;
    pA[i] = g + (size_t)rl*KDIM + gc*8;
  }
  const __hip_bfloat16* pB[2];
  #pragma unroll
  for (int i = 0; i < 2; ++i)
    pB[i] = Wt + (size_t)(c0 + i*32 + (tid >> 3))*KDIM + gc*8;

  if (tid < BM) bid[tid] = (r0 + tid < Ma) ? bidc[r0 + tid] : -1;
  for (int z = tid; z < NB*BN; z += 256) (&psum[0][0])[z] = 0.0f;

  f32x4 acc[2][2] = {};

  for (int kt = 0; kt < NKT; ++kt) {
    int k0 = kt*BK;
    #pragma unroll
    for (int i = 0; i < 2; ++i) GLD16(pA[i] + k0, lA + (i*256 + tid)*16);
    #pragma unroll
    for (int i = 0; i < 2; ++i) GLD16(pB[i] + k0, lB + (i*256 + tid)*16);
    __syncthreads();
    #pragma unroll
    for (int ks = 0; ks < 2; ++ks) {
      bf16x8 af[2], bfr[2];
      #pragma unroll
      for (int m = 0; m < 2; ++m) {
        int row = wr*32 + m*16 + (lane & 15);
        int ch = (ks*4 + (lane >> 4)) ^ (row & 7);
        af[m] = *(const bf16x8*)(lA + row*128 + ch*16);
      }
      #pragma unroll
      for (int n = 0; n < 2; ++n) {
        int row = wc*32 + n*16 + (lane & 15);
        int ch = (ks*4 + (lane >> 4)) ^ (row & 7);
        bfr[n] = *(const bf16x8*)(lB + row*128 + ch*16);
      }
      #pragma unroll
      for (int m = 0; m < 2; ++m)
        #pragma unroll
        for (int n = 0; n < 2; ++n)
          acc[m][n] = __builtin_amdgcn_mfma_f32_16x16x32_bf16(af[m], bfr[n], acc[m][n], 0, 0, 0);
    }
    __syncthreads();
  }

  // ---- epilogue: leaky + deterministic per-batch column sums ----
  int q = lane >> 4;
  #pragma unroll 1
  for (int phase = 0; phase < 8; ++phase) {
    if (wr*4 + q == phase) {
      #pragma unroll
      for (int n = 0; n < 2; ++n) {
        int c = wc*32 + n*16 + (lane & 15);
        float run = 0.0f; int curb = -2;
        #pragma unroll
        for (int m = 0; m < 2; ++m) {
          #pragma unroll
          for (int j = 0; j < 4; ++j) {
            int r = wr*32 + m*16 + q*4 + j;
            int b = bid[r];
            float v = acc[m][n][j];
            v = v > 0.0f ? v : 0.1f*v;
            if (b != curb) { if (curb >= 0) psum[curb][c] += run; run = 0.0f; curb = b; }
            run += v;
          }
        }
        if (curb >= 0) psum[curb][c] += run;
      }
    }
    __syncthreads();
  }
  for (int z = tid; z < NB*BN; z += 256) {
    int b = z >> 6, c = z & 63;
    partial[((size_t)rb*NB + b)*DOUT + c0 + c] = psum[b][c];
  }
}

// ---------------- Kernel 3: fused reduce+mean+MLP layer 1 (split-K) ---------
// All 512 threads participate in the rb-reduction (4 segments x 128 cols).
__global__ __launch_bounds__(512) void mlpA_kernel(
    const float* __restrict__ partial, const int* __restrict__ batch,
    const int* __restrict__ mact, const float* __restrict__ w1,
    float* __restrict__ part1) {
  __shared__ float red[4][128];
  __shared__ float pl[128];
  int s = blockIdx.x, b = blockIdx.y, t = threadIdx.x;
  int nact = (*mact + BM - 1) / BM;
  int seg = t >> 7, c = t & 127;
  float v = 0.0f;
  for (int rb = seg; rb < nact; rb += 4)
    v += partial[((size_t)rb*NB + b)*DOUT + s*128 + c];
  red[seg][c] = v;
  __syncthreads();
  if (t < 128) {
    float sum = (red[0][t] + red[1][t]) + (red[2][t] + red[3][t]);
    int lb, ub;
    { int l = 0, r = N_PTS; while (l < r) { int m = (l+r)>>1; if (batch[m] <  b) l = m+1; else r = m; } lb = l; }
    { int l = 0, r = N_PTS; while (l < r) { int m = (l+r)>>1; if (batch[m] <= b) l = m+1; else r = m; } ub = l; }
    pl[t] = sum / fmaxf((float)(ub - lb), 1.0f);
  }
  __syncthreads();
  float acc = 0.0f;
  #pragma unroll 8
  for (int i = 0; i < 128; ++i) acc += pl[i] * w1[(size_t)(s*128 + i)*512 + t];
  part1[((size_t)b*8 + s)*512 + t] = acc;
}

// ---------------- Kernel 4: fused MLP layers 2+3 ----------------------------
__global__ __launch_bounds__(256) void mlpBC_kernel(
    const float* __restrict__ part1, const float* __restrict__ b1,
    const float* __restrict__ w2, const float* __restrict__ b2,
    const float* __restrict__ w3, const float* __restrict__ b3,
    float* __restrict__ out) {
  __shared__ float hs[512];
  __shared__ float h2l[256];
  int b = blockIdx.x, t = threadIdx.x;
  for (int u = t; u < 512; u += 256) {
    float v = b1[u];
    #pragma unroll
    for (int s = 0; s < 8; ++s) v += part1[((size_t)b*8 + s)*512 + u];
    hs[u] = fmaxf(v, 0.0f);
  }
  __syncthreads();
  float a2 = b2[t];
  #pragma unroll 8
  for (int j = 0; j < 512; ++j) a2 += hs[j] * w2[(size_t)j*256 + t];
  h2l[t] = fmaxf(a2, 0.0f);
  __syncthreads();
  if (t < 152) {
    float a3 = b3[t];
    #pragma unroll 8
    for (int i = 0; i < 256; ++i) a3 += h2l[i] * w3[i*152 + t];
    out[b*152 + t] = a3;
  }
}

// ---------------- launch -----------------------------------------------------
extern "C" void kernel_launch(void* const* d_in, const int* in_sizes, int n_in,
                              void* d_out, int out_size, void* d_ws, size_t ws_size,
                              hipStream_t stream) {
  (void)in_sizes; (void)n_in; (void)out_size; (void)ws_size;
  const float* pos   = (const float*)d_in[0];
  const float* feats = (const float*)d_in[1];
  const float* kpts  = (const float*)d_in[2];
  const float* kpw   = (const float*)d_in[3];
  const float* w1    = (const float*)d_in[4];
  const float* b1    = (const float*)d_in[5];
  const float* w2    = (const float*)d_in[6];
  const float* b2    = (const float*)d_in[7];
  const float* w3    = (const float*)d_in[8];
  const float* b3    = (const float*)d_in[9];
  const int* nidx    = (const int*)d_in[10];
  const int* batch   = (const int*)d_in[11];
  float* out = (float*)d_out;

  char* ws = (char*)d_ws;
  const size_t off_g        = 0;                         // 50000*960*2 = 96,000,000
  const size_t off_bidc     = 96000000;                  // 200,704
  const size_t off_rowlist  = off_bidc + 200704;
  const size_t off_flag     = off_rowlist + 200704;
  const size_t off_bcnt     = off_flag + 200704;         // 1024
  const size_t off_boff     = off_bcnt + 1024;           // 1024
  const size_t off_mact     = off_boff + 1024;           // 64
  const size_t off_wt       = off_mact + 64;             // 1,966,080
  const size_t off_partial  = off_wt + 1966080;          // 784*16*1024*4 = 51,380,224
  const size_t off_p1       = off_partial + 51380224;    // 262,144 (total ~150MB)
  __hip_bfloat16* g  = (__hip_bfloat16*)(ws + off_g);
  int* bidc    = (int*)(ws + off_bidc);
  int* rowlist = (int*)(ws + off_rowlist);
  int* flag    = (int*)(ws + off_flag);
  int* bcnt    = (int*)(ws + off_bcnt);
  int* boff    = (int*)(ws + off_boff);
  int* mact    = (int*)(ws + off_mact);
  __hip_bfloat16* wt = (__hip_bfloat16*)(ws + off_wt);
  float* partial = (float*)(ws + off_partial);
  float* part1   = (float*)(ws + off_p1);

  wt_kernel<<<dim3(KDIM/64, DOUT/64), 256, 0, stream>>>(kpw, wt, bcnt);
  kpconv_full_kernel<<<(N_PTS+3)/4, 256, 0, stream>>>(pos, feats, kpts, nidx, g, flag, bcnt);
  scan_kernel<<<1, 256, 0, stream>>>(bcnt, boff, mact);
  fill_kernel<<<NSEG, 256, 0, stream>>>(flag, boff, batch, rowlist, bidc);
  gemm_mfma_pool<<<dim3(RB_FULL, DOUT/BN), 256, 0, stream>>>(g, wt, rowlist, bidc, mact, partial);
  mlpA_kernel<<<dim3(8, NB), 512, 0, stream>>>(partial, batch, mact, w1, part1);
  mlpBC_kernel<<<NB, 256, 0, stream>>>(part1, b1, w2, b2, w3, b3, out);
}

// Round 14
// 193.036 us; speedup vs baseline: 1.3321x; 1.0700x over previous
//
#include <hip/hip_runtime.h>
#include <hip/hip_bf16.h>

#define N_PTS 50000
#define NNB   32
#define KP    15
#define DIN   64
#define DOUT  1024
#define KDIM  (KP*DIN)    // 960
#define NB    16
#define SIGMA_INV (1.0f/0.3f)

#define BM 64
#define BN 64
#define BK 64
#define NKT (KDIM/BK)               // 15
#define RB_FULL 784                 // worst-case row blocks (50176 rows), %8==0
#define NCB (DOUT/BN)               // 16
#define NWG (RB_FULL*NCB)           // 12544
#define NSEG 196                    // 256-point segments

typedef __attribute__((ext_vector_type(8))) short bf16x8;
typedef __attribute__((ext_vector_type(4))) float f32x4;

#define GLD16(gsrc, ldst) \
  __builtin_amdgcn_global_load_lds((const __attribute__((address_space(1))) char*)(gsrc), \
                                   (__attribute__((address_space(3))) char*)(ldst), 16, 0, 0)

// ---------------- Kernel 0: W transpose to bf16 [1024][960]; zeroes bcnt -----
__global__ __launch_bounds__(256) void wt_kernel(
    const float* __restrict__ W, __hip_bfloat16* __restrict__ Wt,
    int* __restrict__ bcnt) {
  if (blockIdx.x == 0 && blockIdx.y == 0 && threadIdx.x < 256)
    bcnt[threadIdx.x] = 0;                      // runs before kpconv (stream order)
  __shared__ float t[64][65];
  int k0 = blockIdx.x * 64;
  int o0 = blockIdx.y * 64;
  int tx = threadIdx.x & 63, ty = threadIdx.x >> 6;
  for (int r = ty; r < 64; r += 4) t[r][tx] = W[(size_t)(k0 + r)*DOUT + o0 + tx];
  __syncthreads();
  for (int r = ty; r < 64; r += 4)
    Wt[(size_t)(o0 + r)*KDIM + k0 + tx] = __float2bfloat16(t[tx][r]);
}

// ---------------- Kernel 1: KPConv full — flag + g row, one wave/point ------
__global__ __launch_bounds__(256) void kpconv_full_kernel(
    const float* __restrict__ pos, const float* __restrict__ feats,
    const float* __restrict__ kpts, const int* __restrict__ nidx,
    __hip_bfloat16* __restrict__ g, int* __restrict__ flag,
    int* __restrict__ bcnt) {
  __shared__ float h_lds[4][16][33];
  __shared__ int cnts;
  int tid = threadIdx.x;
  int w = tid >> 6, lane = tid & 63;
  if (tid == 0) cnts = 0;
  __syncthreads();
  int n = blockIdx.x * 4 + w;
  if (n < N_PTS) {
    int myj = lane & 31;
    int khalf = lane >> 5;
    int id0 = nidx[n*NNB + myj];
    float px = pos[n*3+0], py = pos[n*3+1], pz = pos[n*3+2];
    float rx = pos[id0*3+0] - px;
    float ry = pos[id0*3+1] - py;
    float rz = pos[id0*3+2] - pz;
    bool anyact = false;
    float hreg[8];
    #pragma unroll
    for (int i = 0; i < 8; ++i) {
      int k = 2*i + khalf;
      float h = 0.0f;
      if (k < KP) {
        float dx = rx - kpts[k*3+0];
        float dy = ry - kpts[k*3+1];
        float dz = rz - kpts[k*3+2];
        float d = sqrtf(dx*dx + dy*dy + dz*dz);
        h = 1.0f - d * SIGMA_INV;
        h = h > 0.0f ? h : 0.0f;
        anyact |= (h > 0.0f);
      }
      hreg[i] = h;
    }
    unsigned long long bal = __ballot(anyact);
    if (bal) {                                  // wave-uniform
      unsigned int actj = (unsigned int)(bal | (bal >> 32));
      if ((actj >> myj) & 1) {
        #pragma unroll
        for (int i = 0; i < 8; ++i) {
          int k = 2*i + khalf;
          if (k < KP) h_lds[w][k][myj] = hreg[i];
        }
      }
      float acc[KP];
      #pragma unroll
      for (int k = 0; k < KP; ++k) acc[k] = 0.0f;
      while (actj) {
        int j = __ffs(actj) - 1;
        actj &= actj - 1;
        int id = __shfl(id0, j);
        float f = feats[(size_t)id*DIN + lane];
        #pragma unroll
        for (int k = 0; k < KP; ++k) acc[k] += h_lds[w][k][j] * f;
      }
      size_t base = (size_t)n*KDIM;
      #pragma unroll
      for (int k = 0; k < KP; ++k)
        g[base + k*DIN + lane] = __float2bfloat16(acc[k]);
    }
    if (lane == 0) {
      int active = (bal != 0ull) ? 1 : 0;
      flag[n] = active;
      if (active) atomicAdd(&cnts, 1);
    }
  }
  __syncthreads();
  if (tid == 0 && cnts) atomicAdd(&bcnt[blockIdx.x >> 6], cnts);
}

// ---------------- Kernel C0: fill rowlist + bidc (self-scanning) ------------
// Each block computes its own segment offset from the 196 bcnt values
// (folds the old scan kernel away); block NSEG-1 also writes mact.
__global__ __launch_bounds__(256) void fill_kernel(
    const int* __restrict__ flag, const int* __restrict__ bcnt,
    const int* __restrict__ batch, int* __restrict__ rowlist,
    int* __restrict__ bidc, int* __restrict__ mact) {
  __shared__ int s[256];
  __shared__ int boff_l;
  int tid = threadIdx.x;
  // in-block: sum bcnt[0..bid-1] via 256-thread scan of the 196 counts
  int bc = (tid < NSEG) ? bcnt[tid] : 0;
  s[tid] = (tid < (int)blockIdx.x) ? bc : 0;
  __syncthreads();
  for (int d = 1; d < 256; d <<= 1) {
    int v = (tid >= d) ? s[tid-d] : 0;
    __syncthreads();
    s[tid] += v;
    __syncthreads();
  }
  if (tid == 255) boff_l = s[255];
  __syncthreads();
  int boff = boff_l;
  // per-point scan of this segment's flags
  int n = blockIdx.x*256 + tid;
  int f = (n < N_PTS) ? flag[n] : 0;
  s[tid] = f;
  __syncthreads();
  for (int d = 1; d < 256; d <<= 1) {
    int v = (tid >= d) ? s[tid-d] : 0;
    __syncthreads();
    s[tid] += v;
    __syncthreads();
  }
  if (f) {
    int sl = boff + s[tid] - 1;
    rowlist[sl] = n;
    bidc[sl] = batch[n];
  }
  if (blockIdx.x == NSEG-1 && tid == 255) *mact = boff + s[255];
}

// ---------------- Kernel 2: MFMA GEMM (gathered A rows) + fused pool --------
// 64x64 tile, BK=64, 4 waves 2x2. R13 inner loop unchanged. NEW: temporal
// XCD locality — 1-D grid, mapping g=wg&7, t=wg>>3, rb=(t>>4)*8+g, cb=t&15.
// XCD = wg%8 = g, rb%8 == g (same placement as R13), but cb is now the
// FASTEST dimension per XCD: the 16 blocks sharing an A-panel run
// back-to-back, keeping the panel (120KB) + full B (2MB) L2-resident.
// Active rbs (rb%8 uniform) spread evenly over XCDs.
__global__ __launch_bounds__(256) void gemm_mfma_pool(
    const __hip_bfloat16* __restrict__ g, const __hip_bfloat16* __restrict__ Wt,
    const int* __restrict__ rowlist, const int* __restrict__ bidc,
    const int* __restrict__ mact, float* __restrict__ partial) {
  __shared__ __align__(16) char lA[BM*128];  // 8KB
  __shared__ __align__(16) char lB[BN*128];  // 8KB
  __shared__ float psum[NB][BN];             // 4KB
  __shared__ int bid[BM];
  int wg = blockIdx.x;
  int xg = wg & 7, t = wg >> 3;
  int rb = ((t >> 4) << 3) + xg;              // bijective onto [0,784)
  int cb = t & 15;
  int Ma = *mact;
  int r0 = rb*BM, c0 = cb*BN;
  int tid = threadIdx.x;
  if (r0 >= Ma) return;
  int lane = tid & 63, w = tid >> 6;
  int wr = w >> 1, wc = w & 1;

  // hoisted gather bases; gc uniform over i (rows i*32+(tid>>3), 32%8==0)
  int gc = (tid & 7) ^ ((tid >> 3) & 7);
  const __hip_bfloat16* pA[2];
  #pragma unroll
  for (int i = 0; i < 2; ++i) {
    int slot = r0 + i*32 + (tid >> 3);
    int rl = (slot < Ma) ? rowlist[slot] : 0;
    pA[i] = g + (size_t)rl*KDIM + gc*8;
  }
  const __hip_bfloat16* pB[2];
  #pragma unroll
  for (int i = 0; i < 2; ++i)
    pB[i] = Wt + (size_t)(c0 + i*32 + (tid >> 3))*KDIM + gc*8;

  if (tid < BM) bid[tid] = (r0 + tid < Ma) ? bidc[r0 + tid] : -1;
  for (int z = tid; z < NB*BN; z += 256) (&psum[0][0])[z] = 0.0f;

  f32x4 acc[2][2] = {};

  for (int kt = 0; kt < NKT; ++kt) {
    int k0 = kt*BK;
    #pragma unroll
    for (int i = 0; i < 2; ++i) GLD16(pA[i] + k0, lA + (i*256 + tid)*16);
    #pragma unroll
    for (int i = 0; i < 2; ++i) GLD16(pB[i] + k0, lB + (i*256 + tid)*16);
    __syncthreads();
    #pragma unroll
    for (int ks = 0; ks < 2; ++ks) {
      bf16x8 af[2], bfr[2];
      #pragma unroll
      for (int m = 0; m < 2; ++m) {
        int row = wr*32 + m*16 + (lane & 15);
        int ch = (ks*4 + (lane >> 4)) ^ (row & 7);
        af[m] = *(const bf16x8*)(lA + row*128 + ch*16);
      }
      #pragma unroll
      for (int n = 0; n < 2; ++n) {
        int row = wc*32 + n*16 + (lane & 15);
        int ch = (ks*4 + (lane >> 4)) ^ (row & 7);
        bfr[n] = *(const bf16x8*)(lB + row*128 + ch*16);
      }
      #pragma unroll
      for (int m = 0; m < 2; ++m)
        #pragma unroll
        for (int n = 0; n < 2; ++n)
          acc[m][n] = __builtin_amdgcn_mfma_f32_16x16x32_bf16(af[m], bfr[n], acc[m][n], 0, 0, 0);
    }
    __syncthreads();
  }

  // ---- epilogue: leaky + deterministic per-batch column sums ----
  int q = lane >> 4;
  #pragma unroll 1
  for (int phase = 0; phase < 8; ++phase) {
    if (wr*4 + q == phase) {
      #pragma unroll
      for (int n = 0; n < 2; ++n) {
        int c = wc*32 + n*16 + (lane & 15);
        float run = 0.0f; int curb = -2;
        #pragma unroll
        for (int m = 0; m < 2; ++m) {
          #pragma unroll
          for (int j = 0; j < 4; ++j) {
            int r = wr*32 + m*16 + q*4 + j;
            int b = bid[r];
            float v = acc[m][n][j];
            v = v > 0.0f ? v : 0.1f*v;
            if (b != curb) { if (curb >= 0) psum[curb][c] += run; run = 0.0f; curb = b; }
            run += v;
          }
        }
        if (curb >= 0) psum[curb][c] += run;
      }
    }
    __syncthreads();
  }
  for (int z = tid; z < NB*BN; z += 256) {
    int b = z >> 6, c = z & 63;
    partial[((size_t)rb*NB + b)*DOUT + c0 + c] = psum[b][c];
  }
}

// ---------------- Kernel 3: fused reduce+mean+MLP layer 1 (split-K) ---------
__global__ __launch_bounds__(512) void mlpA_kernel(
    const float* __restrict__ partial, const int* __restrict__ batch,
    const int* __restrict__ mact, const float* __restrict__ w1,
    float* __restrict__ part1) {
  __shared__ float red[4][128];
  __shared__ float pl[128];
  int s = blockIdx.x, b = blockIdx.y, t = threadIdx.x;
  int nact = (*mact + BM - 1) / BM;
  int seg = t >> 7, c = t & 127;
  float v = 0.0f;
  for (int rb = seg; rb < nact; rb += 4)
    v += partial[((size_t)rb*NB + b)*DOUT + s*128 + c];
  red[seg][c] = v;
  __syncthreads();
  if (t < 128) {
    float sum = (red[0][t] + red[1][t]) + (red[2][t] + red[3][t]);
    int lb, ub;
    { int l = 0, r = N_PTS; while (l < r) { int m = (l+r)>>1; if (batch[m] <  b) l = m+1; else r = m; } lb = l; }
    { int l = 0, r = N_PTS; while (l < r) { int m = (l+r)>>1; if (batch[m] <= b) l = m+1; else r = m; } ub = l; }
    pl[t] = sum / fmaxf((float)(ub - lb), 1.0f);
  }
  __syncthreads();
  float acc = 0.0f;
  #pragma unroll 8
  for (int i = 0; i < 128; ++i) acc += pl[i] * w1[(size_t)(s*128 + i)*512 + t];
  part1[((size_t)b*8 + s)*512 + t] = acc;
}

// ---------------- Kernel 4: fused MLP layers 2+3 ----------------------------
__global__ __launch_bounds__(256) void mlpBC_kernel(
    const float* __restrict__ part1, const float* __restrict__ b1,
    const float* __restrict__ w2, const float* __restrict__ b2,
    const float* __restrict__ w3, const float* __restrict__ b3,
    float* __restrict__ out) {
  __shared__ float hs[512];
  __shared__ float h2l[256];
  int b = blockIdx.x, t = threadIdx.x;
  for (int u = t; u < 512; u += 256) {
    float v = b1[u];
    #pragma unroll
    for (int s = 0; s < 8; ++s) v += part1[((size_t)b*8 + s)*512 + u];
    hs[u] = fmaxf(v, 0.0f);
  }
  __syncthreads();
  float a2 = b2[t];
  #pragma unroll 8
  for (int j = 0; j < 512; ++j) a2 += hs[j] * w2[(size_t)j*256 + t];
  h2l[t] = fmaxf(a2, 0.0f);
  __syncthreads();
  if (t < 152) {
    float a3 = b3[t];
    #pragma unroll 8
    for (int i = 0; i < 256; ++i) a3 += h2l[i] * w3[i*152 + t];
    out[b*152 + t] = a3;
  }
}

// ---------------- launch -----------------------------------------------------
extern "C" void kernel_launch(void* const* d_in, const int* in_sizes, int n_in,
                              void* d_out, int out_size, void* d_ws, size_t ws_size,
                              hipStream_t stream) {
  (void)in_sizes; (void)n_in; (void)out_size; (void)ws_size;
  const float* pos   = (const float*)d_in[0];
  const float* feats = (const float*)d_in[1];
  const float* kpts  = (const float*)d_in[2];
  const float* kpw   = (const float*)d_in[3];
  const float* w1    = (const float*)d_in[4];
  const float* b1    = (const float*)d_in[5];
  const float* w2    = (const float*)d_in[6];
  const float* b2    = (const float*)d_in[7];
  const float* w3    = (const float*)d_in[8];
  const float* b3    = (const float*)d_in[9];
  const int* nidx    = (const int*)d_in[10];
  const int* batch   = (const int*)d_in[11];
  float* out = (float*)d_out;

  char* ws = (char*)d_ws;
  const size_t off_g        = 0;                         // 50000*960*2 = 96,000,000
  const size_t off_bidc     = 96000000;                  // 200,704
  const size_t off_rowlist  = off_bidc + 200704;
  const size_t off_flag     = off_rowlist + 200704;
  const size_t off_bcnt     = off_flag + 200704;         // 1024
  const size_t off_mact     = off_bcnt + 1024;           // 64
  const size_t off_wt       = off_mact + 64;             // 1,966,080
  const size_t off_partial  = off_wt + 1966080;          // 784*16*1024*4 = 51,380,224
  const size_t off_p1       = off_partial + 51380224;    // 262,144 (total ~150MB)
  __hip_bfloat16* g  = (__hip_bfloat16*)(ws + off_g);
  int* bidc    = (int*)(ws + off_bidc);
  int* rowlist = (int*)(ws + off_rowlist);
  int* flag    = (int*)(ws + off_flag);
  int* bcnt    = (int*)(ws + off_bcnt);
  int* mact    = (int*)(ws + off_mact);
  __hip_bfloat16* wt = (__hip_bfloat16*)(ws + off_wt);
  float* partial = (float*)(ws + off_partial);
  float* part1   = (float*)(ws + off_p1);

  wt_kernel<<<dim3(KDIM/64, DOUT/64), 256, 0, stream>>>(kpw, wt, bcnt);
  kpconv_full_kernel<<<(N_PTS+3)/4, 256, 0, stream>>>(pos, feats, kpts, nidx, g, flag, bcnt);
  fill_kernel<<<NSEG, 256, 0, stream>>>(flag, bcnt, batch, rowlist, bidc, mact);
  gemm_mfma_pool<<<NWG, 256, 0, stream>>>(g, wt, rowlist, bidc, mact, partial);
  mlpA_kernel<<<dim3(8, NB), 512, 0, stream>>>(partial, batch, mact, w1, part1);
  mlpBC_kernel<<<NB, 256, 0, stream>>>(part1, b1, w2, b2, w3, b3, out);
}